// Round 6
// baseline (335.556 us; speedup 1.0000x reference)
//
#include <hip/hip_runtime.h>

// ---------------------------------------------------------------------------
// GIN 2-layer forward. R6: feature-split agg256 (2 waves/node, unroll 8),
// unroll-8 agg128, fused prep kernel (zero+cast+transposes).
// bf16 MFMA GEMMs (16x16x32), CSR-gather aggregation, hierarchical scan.
//   conv(x) = mlp(x + segment_sum(x[src], dst)); mlp = Lin->ReLU->Lin
// N=50000, E=600000, dims 128->256->256->256->128.
// ---------------------------------------------------------------------------

typedef __bf16 bf16x8 __attribute__((ext_vector_type(8)));
typedef float f32x4 __attribute__((ext_vector_type(4)));
typedef unsigned short u16x4 __attribute__((ext_vector_type(4)));
typedef unsigned short u16x2 __attribute__((ext_vector_type(2)));
typedef unsigned int uint32;

__device__ __forceinline__ unsigned short f2bf(float f) {
  uint32 u = __builtin_bit_cast(uint32, f);
  u += 0x7FFFu + ((u >> 16) & 1u);  // RNE
  return (unsigned short)(u >> 16);
}
__device__ __forceinline__ float bf2f(unsigned short h) {
  return __builtin_bit_cast(float, (uint32)h << 16);
}

#define G2L16(gp, lp)                                                        \
  __builtin_amdgcn_global_load_lds(                                          \
      (const __attribute__((address_space(1))) void*)(gp),                   \
      (__attribute__((address_space(3))) void*)(lp), 16, 0, 0)

// ---------------------------- CSR build ------------------------------------
__global__ void hist(const int* __restrict__ eidx, int* __restrict__ deg, int E) {
  int e = blockIdx.x * blockDim.x + threadIdx.x;
  if (e < E) atomicAdd(&deg[eidx[e + E]], 1);
}

__global__ __launch_bounds__(256) void block_sums(const int* __restrict__ deg,
                                                  int* __restrict__ bsum, int Nn) {
  __shared__ int sm[256];
  int t = threadIdx.x;
  int i = blockIdx.x * 256 + t;
  sm[t] = (i < Nn) ? deg[i] : 0;
  __syncthreads();
#pragma unroll
  for (int off = 128; off > 0; off >>= 1) {
    if (t < off) sm[t] += sm[t + off];
    __syncthreads();
  }
  if (t == 0) bsum[blockIdx.x] = sm[0];
}

__global__ __launch_bounds__(256) void scan_bsums(int* __restrict__ bsum, int nb) {
  __shared__ int sm[256];
  int t = threadIdx.x;
  int v = (t < nb) ? bsum[t] : 0;
  sm[t] = v;
  __syncthreads();
#pragma unroll
  for (int off = 1; off < 256; off <<= 1) {
    int add = (t >= off) ? sm[t - off] : 0;
    __syncthreads();
    sm[t] += add;
    __syncthreads();
  }
  if (t < nb) bsum[t] = sm[t] - v;  // exclusive
}

__global__ __launch_bounds__(256) void block_scan(const int* __restrict__ deg,
                                                  const int* __restrict__ bsum,
                                                  int* __restrict__ offs,
                                                  int* __restrict__ pos, int Nn) {
  __shared__ int sm[256];
  int t = threadIdx.x;
  int i = blockIdx.x * 256 + t;
  int v = (i < Nn) ? deg[i] : 0;
  sm[t] = v;
  __syncthreads();
#pragma unroll
  for (int off = 1; off < 256; off <<= 1) {
    int add = (t >= off) ? sm[t - off] : 0;
    __syncthreads();
    sm[t] += add;
    __syncthreads();
  }
  int ex = bsum[blockIdx.x] + sm[t] - v;
  if (i < Nn) {
    offs[i] = ex;
    pos[i] = ex;
    if (i == Nn - 1) offs[Nn] = ex + v;
  }
}

__global__ void fill_csr(const int* __restrict__ eidx, int* __restrict__ pos,
                         int* __restrict__ esrc, int E) {
  int e = blockIdx.x * blockDim.x + threadIdx.x;
  if (e < E) {
    int s = eidx[e];
    int d = eidx[e + E];
    int p = atomicAdd(&pos[d], 1);
    esrc[p] = s;
  }
}

// --------------- fused prep: zero deg + cast x->bf16 + transposes -----------
// blocks [0,zb): zero deg; [zb, zb+768): weight transpose; rest: cast x.
__global__ __launch_bounds__(256) void prep(
    int* __restrict__ deg, int Nn,
    const float* __restrict__ x, unsigned short* __restrict__ xb, long long n4,
    const float* __restrict__ W1a, const float* __restrict__ W2a,
    const float* __restrict__ W1b, const float* __restrict__ W2b,
    unsigned short* __restrict__ w1t, unsigned short* __restrict__ w2t,
    unsigned short* __restrict__ w3t, unsigned short* __restrict__ w4t) {
  int zb = (Nn + 255) >> 8;
  int b = blockIdx.x;
  int t = threadIdx.x;
  if (b < zb) {
    int i = b * 256 + t;
    if (i < Nn) deg[i] = 0;
  } else if (b < zb + 768) {
    int i = (b - zb) * 256 + t;  // 0..196607
    const float* W;
    unsigned short* WT;
    int K, N, j;
    if (i < 32768) {            // W1a: 128x256
      W = W1a; WT = w1t; K = 128; N = 256; j = i;
    } else if (i < 98304) {     // W2a: 256x256
      W = W2a; WT = w2t; K = 256; N = 256; j = i - 32768;
    } else if (i < 163840) {    // W1b: 256x256
      W = W1b; WT = w3t; K = 256; N = 256; j = i - 98304;
    } else {                    // W2b: 256x128
      W = W2b; WT = w4t; K = 256; N = 128; j = i - 163840;
    }
    int k = j / N, n = j - k * N;
    WT[n * K + k] = f2bf(W[j]);
  } else {
    long long i = (long long)(b - zb - 768) * 256 + t;
    long long stride = (long long)(gridDim.x - zb - 768) * 256;
    for (; i < n4; i += stride) {
      float4 v = ((const float4*)x)[i];
      u16x4 o;
      o.x = f2bf(v.x); o.y = f2bf(v.y); o.z = f2bf(v.z); o.w = f2bf(v.w);
      ((u16x4*)xb)[i] = o;
    }
  }
}

// ------------------------- aggregation -------------------------------------
// D=128 bf16 gather: one wave per node, u16x2/lane, 8 loads in flight.
__global__ __launch_bounds__(256) void agg_bf16_128(
    unsigned short* __restrict__ out, const unsigned short* __restrict__ xb,
    const int* __restrict__ offs, const int* __restrict__ esrc, int Nn) {
  int node = blockIdx.x * 4 + (threadIdx.x >> 6);
  int lane = threadIdx.x & 63;
  if (node >= Nn) return;
  int beg = offs[node], end = offs[node + 1];
  const unsigned short* xp = xb + lane * 2;
  u16x2 sv = *(const u16x2*)(xp + (long long)node * 128);
  float a0 = bf2f(sv.x), a1 = bf2f(sv.y);
  float b0 = 0.f, b1 = 0.f, c0 = 0.f, c1 = 0.f, d0 = 0.f, d1 = 0.f;
  int n = beg;
  for (; n + 7 < end; n += 8) {
    u16x2 v0 = *(const u16x2*)(xp + (long long)esrc[n] * 128);
    u16x2 v1 = *(const u16x2*)(xp + (long long)esrc[n + 1] * 128);
    u16x2 v2 = *(const u16x2*)(xp + (long long)esrc[n + 2] * 128);
    u16x2 v3 = *(const u16x2*)(xp + (long long)esrc[n + 3] * 128);
    u16x2 v4 = *(const u16x2*)(xp + (long long)esrc[n + 4] * 128);
    u16x2 v5 = *(const u16x2*)(xp + (long long)esrc[n + 5] * 128);
    u16x2 v6 = *(const u16x2*)(xp + (long long)esrc[n + 6] * 128);
    u16x2 v7 = *(const u16x2*)(xp + (long long)esrc[n + 7] * 128);
    a0 += bf2f(v0.x); a1 += bf2f(v0.y);
    b0 += bf2f(v1.x); b1 += bf2f(v1.y);
    c0 += bf2f(v2.x); c1 += bf2f(v2.y);
    d0 += bf2f(v3.x); d1 += bf2f(v3.y);
    a0 += bf2f(v4.x); a1 += bf2f(v4.y);
    b0 += bf2f(v5.x); b1 += bf2f(v5.y);
    c0 += bf2f(v6.x); c1 += bf2f(v6.y);
    d0 += bf2f(v7.x); d1 += bf2f(v7.y);
  }
  for (; n < end; ++n) {
    u16x2 v0 = *(const u16x2*)(xp + (long long)esrc[n] * 128);
    a0 += bf2f(v0.x); a1 += bf2f(v0.y);
  }
  a0 += b0 + c0 + d0;
  a1 += b1 + c1 + d1;
  u16x2 o; o.x = f2bf(a0); o.y = f2bf(a1);
  *(u16x2*)(out + (long long)node * 128 + lane * 2) = o;
}

// D=256 bf16 gather, feature-split: 2 waves per node (128 feats each),
// u16x2/lane, 8 loads in flight.
__global__ __launch_bounds__(256) void agg_bf16_256s(
    unsigned short* __restrict__ out, const unsigned short* __restrict__ h,
    const int* __restrict__ offs, const int* __restrict__ esrc, int Nn) {
  int idx = blockIdx.x * 4 + (threadIdx.x >> 6);  // wave index
  int node = idx >> 1;
  if (node >= Nn) return;
  int half = idx & 1;
  int lane = threadIdx.x & 63;
  int beg = offs[node], end = offs[node + 1];
  const unsigned short* hp = h + half * 128 + lane * 2;
  u16x2 sv = *(const u16x2*)(hp + (long long)node * 256);
  float a0 = bf2f(sv.x), a1 = bf2f(sv.y);
  float b0 = 0.f, b1 = 0.f, c0 = 0.f, c1 = 0.f, d0 = 0.f, d1 = 0.f;
  int n = beg;
  for (; n + 7 < end; n += 8) {
    u16x2 v0 = *(const u16x2*)(hp + (long long)esrc[n] * 256);
    u16x2 v1 = *(const u16x2*)(hp + (long long)esrc[n + 1] * 256);
    u16x2 v2 = *(const u16x2*)(hp + (long long)esrc[n + 2] * 256);
    u16x2 v3 = *(const u16x2*)(hp + (long long)esrc[n + 3] * 256);
    u16x2 v4 = *(const u16x2*)(hp + (long long)esrc[n + 4] * 256);
    u16x2 v5 = *(const u16x2*)(hp + (long long)esrc[n + 5] * 256);
    u16x2 v6 = *(const u16x2*)(hp + (long long)esrc[n + 6] * 256);
    u16x2 v7 = *(const u16x2*)(hp + (long long)esrc[n + 7] * 256);
    a0 += bf2f(v0.x); a1 += bf2f(v0.y);
    b0 += bf2f(v1.x); b1 += bf2f(v1.y);
    c0 += bf2f(v2.x); c1 += bf2f(v2.y);
    d0 += bf2f(v3.x); d1 += bf2f(v3.y);
    a0 += bf2f(v4.x); a1 += bf2f(v4.y);
    b0 += bf2f(v5.x); b1 += bf2f(v5.y);
    c0 += bf2f(v6.x); c1 += bf2f(v6.y);
    d0 += bf2f(v7.x); d1 += bf2f(v7.y);
  }
  for (; n < end; ++n) {
    u16x2 v0 = *(const u16x2*)(hp + (long long)esrc[n] * 256);
    a0 += bf2f(v0.x); a1 += bf2f(v0.y);
  }
  a0 += b0 + c0 + d0;
  a1 += b1 + c1 + d1;
  u16x2 o; o.x = f2bf(a0); o.y = f2bf(a1);
  *(u16x2*)(out + (long long)node * 256 + half * 128 + lane * 2) = o;
}

// ----------------------------- MFMA GEMM ------------------------------------
// C[M,N] = A[M,K]@B[K,N] + bias (opt ReLU). A bf16 [M][K], BT bf16 [N][K].
// BM=BN=128, BK=32. 256 threads = 4 waves in 2x2, each wave 64x64 (4x4 tiles
// of 16x16x32 MFMA). global_load_lds width-16 staging.
template <bool RELU, bool OUT_BF16>
__global__ __launch_bounds__(256) void gemm_mfma(
    const unsigned short* __restrict__ A, const unsigned short* __restrict__ BT,
    const float* __restrict__ bias, void* __restrict__ C, int M, int K, int N) {
  __shared__ unsigned short As[128 * 32];
  __shared__ unsigned short Bs[128 * 32];
  const int tid = threadIdx.x;
  const int wave = tid >> 6, lane = tid & 63;
  const int wm = wave & 1, wn = wave >> 1;
  const int quad = lane >> 4, l16 = lane & 15;
  const int rowBase = blockIdx.y * 128;
  const int colBase = blockIdx.x * 128;

  const int srow = wave * 32 + (lane >> 2);
  const int koff = (lane & 3) * 8;
  long long ra0 = min(rowBase + srow, M - 1);
  long long ra1 = min(rowBase + srow + 16, M - 1);
  const unsigned short* ga0 = A + ra0 * K + koff;
  const unsigned short* ga1 = A + ra1 * K + koff;
  const unsigned short* gb0 = BT + (long long)(colBase + srow) * K + koff;
  const unsigned short* gb1 = BT + (long long)(colBase + srow + 16) * K + koff;
  unsigned short* la0 = As + wave * 1024;
  unsigned short* la1 = As + wave * 1024 + 512;
  unsigned short* lb0 = Bs + wave * 1024;
  unsigned short* lb1 = Bs + wave * 1024 + 512;

  f32x4 acc[4][4] = {};

  for (int k0 = 0; k0 < K; k0 += 32) {
    G2L16(ga0, la0);
    G2L16(ga1, la1);
    G2L16(gb0, lb0);
    G2L16(gb1, lb1);
    ga0 += 32; ga1 += 32; gb0 += 32; gb1 += 32;
    __syncthreads();

    bf16x8 af[4], bfr[4];
    const int arow = wm * 64 + l16;
    const int brow = wn * 64 + l16;
#pragma unroll
    for (int mi = 0; mi < 4; ++mi)
      af[mi] = *(const bf16x8*)(As + (arow + mi * 16) * 32 + quad * 8);
#pragma unroll
    for (int ni = 0; ni < 4; ++ni)
      bfr[ni] = *(const bf16x8*)(Bs + (brow + ni * 16) * 32 + quad * 8);
#pragma unroll
    for (int mi = 0; mi < 4; ++mi)
#pragma unroll
      for (int ni = 0; ni < 4; ++ni)
        acc[mi][ni] = __builtin_amdgcn_mfma_f32_16x16x32_bf16(
            af[mi], bfr[ni], acc[mi][ni], 0, 0, 0);
    __syncthreads();
  }

  float bias_v[4];
#pragma unroll
  for (int ni = 0; ni < 4; ++ni)
    bias_v[ni] = bias[colBase + wn * 64 + ni * 16 + l16];
#pragma unroll
  for (int mi = 0; mi < 4; ++mi) {
#pragma unroll
    for (int r = 0; r < 4; ++r) {
      int row = rowBase + wm * 64 + mi * 16 + quad * 4 + r;
      if (row < M) {
#pragma unroll
        for (int ni = 0; ni < 4; ++ni) {
          float o = acc[mi][ni][r] + bias_v[ni];
          if (RELU) o = fmaxf(o, 0.f);
          int col = colBase + wn * 64 + ni * 16 + l16;
          if (OUT_BF16)
            ((unsigned short*)C)[(long long)row * N + col] = f2bf(o);
          else
            ((float*)C)[(long long)row * N + col] = o;
        }
      }
    }
  }
}

// ---------------------------------------------------------------------------
extern "C" void kernel_launch(void* const* d_in, const int* in_sizes, int n_in,
                              void* d_out, int out_size, void* d_ws, size_t ws_size,
                              hipStream_t stream) {
  const float* x   = (const float*)d_in[0];
  const float* W1a = (const float*)d_in[1];
  const float* b1a = (const float*)d_in[2];
  const float* W2a = (const float*)d_in[3];
  const float* b2a = (const float*)d_in[4];
  const float* W1b = (const float*)d_in[5];
  const float* b1b = (const float*)d_in[6];
  const float* W2b = (const float*)d_in[7];
  const float* b2b = (const float*)d_in[8];
  const int*   ei  = (const int*)d_in[9];  // [2,E]: row0=src, row1=dst

  const int Nn = in_sizes[0] / 128;  // 50000
  const int E  = in_sizes[9] / 2;    // 600000
  float* out = (float*)d_out;

  // workspace
  unsigned short* t   = (unsigned short*)d_ws;     // N*256 bf16
  unsigned short* h   = t  + (size_t)Nn * 256;     // N*256
  unsigned short* g0  = h  + (size_t)Nn * 256;     // N*128
  unsigned short* g1  = g0 + (size_t)Nn * 128;     // N*256
  unsigned short* t2  = g1 + (size_t)Nn * 256;     // N*256
  unsigned short* xb  = t2 + (size_t)Nn * 256;     // N*128
  unsigned short* w1t = xb + (size_t)Nn * 128;     // 256*128
  unsigned short* w2t = w1t + 256 * 128;           // 256*256
  unsigned short* w3t = w2t + 256 * 256;           // 256*256
  unsigned short* w4t = w3t + 256 * 256;           // 128*256
  int* deg  = (int*)(w4t + 128 * 256);
  int* offs = deg + Nn;        // N+1
  int* pos  = offs + Nn + 1;   // N
  int* esrc = pos + Nn;        // E
  int* bsum = esrc + E;        // ~196

  dim3 blk(256);
  int nb = (Nn + 255) / 256;  // 196 scan blocks

  // prep: zero deg + cast x->bf16 + weight transposes (one launch)
  prep<<<nb + 768 + 2048, blk, 0, stream>>>(deg, Nn, x, xb,
                                            (long long)Nn * 128 / 4,
                                            W1a, W2a, W1b, W2b,
                                            w1t, w2t, w3t, w4t);
  // CSR build
  hist<<<(E + 255) / 256, blk, 0, stream>>>(ei, deg, E);
  block_sums<<<nb, blk, 0, stream>>>(deg, bsum, Nn);
  scan_bsums<<<1, blk, 0, stream>>>(bsum, nb);
  block_scan<<<nb, blk, 0, stream>>>(deg, bsum, offs, pos, Nn);
  fill_csr<<<(E + 255) / 256, blk, 0, stream>>>(ei, pos, esrc, E);

  int aggBlocks = (Nn + 3) / 4;
  int aggBlocks2 = (2 * Nn + 3) / 4;
  int gy = (Nn + 127) / 128;

  // layer 0
  agg_bf16_128<<<aggBlocks, blk, 0, stream>>>(g0, xb, offs, esrc, Nn);
  gemm_mfma<true, true><<<dim3(2, gy), blk, 0, stream>>>(g0, w1t, b1a, t, Nn, 128, 256);
  gemm_mfma<true, true><<<dim3(2, gy), blk, 0, stream>>>(t, w2t, b2a, h, Nn, 256, 256);

  // layer 1
  agg_bf16_256s<<<aggBlocks2, blk, 0, stream>>>(g1, h, offs, esrc, Nn);
  gemm_mfma<true, true><<<dim3(2, gy), blk, 0, stream>>>(g1, w3t, b1b, t2, Nn, 256, 256);
  gemm_mfma<false, false><<<dim3(1, gy), blk, 0, stream>>>(t2, w4t, b2b, out, Nn, 256, 128);
}

// Round 7
// 312.142 us; speedup vs baseline: 1.0750x; 1.0750x over previous
//
#include <hip/hip_runtime.h>

// ---------------------------------------------------------------------------
// GIN 2-layer forward. R7: multi-row wave gathers, 16B/lane (revert R6 split).
// agg256: 2 rows/load-instr (32 lanes/row), x4 unroll = 8 rows in flight.
// agg128: 4 rows/load-instr (16 lanes/row), x2 unroll = 8 rows in flight.
// bf16 MFMA GEMMs (16x16x32), CSR-gather aggregation, hierarchical scan.
// N=50000, E=600000, dims 128->256->256->256->128.
// ---------------------------------------------------------------------------

typedef __bf16 bf16x8 __attribute__((ext_vector_type(8)));
typedef float f32x4 __attribute__((ext_vector_type(4)));
typedef unsigned short u16x8 __attribute__((ext_vector_type(8)));
typedef unsigned short u16x4 __attribute__((ext_vector_type(4)));
typedef unsigned int uint32;

__device__ __forceinline__ unsigned short f2bf(float f) {
  uint32 u = __builtin_bit_cast(uint32, f);
  u += 0x7FFFu + ((u >> 16) & 1u);  // RNE
  return (unsigned short)(u >> 16);
}
__device__ __forceinline__ float bf2f(unsigned short h) {
  return __builtin_bit_cast(float, (uint32)h << 16);
}

#define G2L16(gp, lp)                                                        \
  __builtin_amdgcn_global_load_lds(                                          \
      (const __attribute__((address_space(1))) void*)(gp),                   \
      (__attribute__((address_space(3))) void*)(lp), 16, 0, 0)

// ---------------------------- CSR build ------------------------------------
__global__ void hist(const int* __restrict__ eidx, int* __restrict__ deg, int E) {
  int e = blockIdx.x * blockDim.x + threadIdx.x;
  if (e < E) atomicAdd(&deg[eidx[e + E]], 1);
}

__global__ __launch_bounds__(256) void block_sums(const int* __restrict__ deg,
                                                  int* __restrict__ bsum, int Nn) {
  __shared__ int sm[256];
  int t = threadIdx.x;
  int i = blockIdx.x * 256 + t;
  sm[t] = (i < Nn) ? deg[i] : 0;
  __syncthreads();
#pragma unroll
  for (int off = 128; off > 0; off >>= 1) {
    if (t < off) sm[t] += sm[t + off];
    __syncthreads();
  }
  if (t == 0) bsum[blockIdx.x] = sm[0];
}

__global__ __launch_bounds__(256) void scan_bsums(int* __restrict__ bsum, int nb) {
  __shared__ int sm[256];
  int t = threadIdx.x;
  int v = (t < nb) ? bsum[t] : 0;
  sm[t] = v;
  __syncthreads();
#pragma unroll
  for (int off = 1; off < 256; off <<= 1) {
    int add = (t >= off) ? sm[t - off] : 0;
    __syncthreads();
    sm[t] += add;
    __syncthreads();
  }
  if (t < nb) bsum[t] = sm[t] - v;  // exclusive
}

__global__ __launch_bounds__(256) void block_scan(const int* __restrict__ deg,
                                                  const int* __restrict__ bsum,
                                                  int* __restrict__ offs,
                                                  int* __restrict__ pos, int Nn) {
  __shared__ int sm[256];
  int t = threadIdx.x;
  int i = blockIdx.x * 256 + t;
  int v = (i < Nn) ? deg[i] : 0;
  sm[t] = v;
  __syncthreads();
#pragma unroll
  for (int off = 1; off < 256; off <<= 1) {
    int add = (t >= off) ? sm[t - off] : 0;
    __syncthreads();
    sm[t] += add;
    __syncthreads();
  }
  int ex = bsum[blockIdx.x] + sm[t] - v;
  if (i < Nn) {
    offs[i] = ex;
    pos[i] = ex;
    if (i == Nn - 1) offs[Nn] = ex + v;
  }
}

__global__ void fill_csr(const int* __restrict__ eidx, int* __restrict__ pos,
                         int* __restrict__ esrc, int E) {
  int e = blockIdx.x * blockDim.x + threadIdx.x;
  if (e < E) {
    int s = eidx[e];
    int d = eidx[e + E];
    int p = atomicAdd(&pos[d], 1);
    esrc[p] = s;
  }
}

// --------------- fused prep: zero deg + cast x->bf16 + transposes -----------
__global__ __launch_bounds__(256) void prep(
    int* __restrict__ deg, int Nn,
    const float* __restrict__ x, unsigned short* __restrict__ xb, long long n4,
    const float* __restrict__ W1a, const float* __restrict__ W2a,
    const float* __restrict__ W1b, const float* __restrict__ W2b,
    unsigned short* __restrict__ w1t, unsigned short* __restrict__ w2t,
    unsigned short* __restrict__ w3t, unsigned short* __restrict__ w4t) {
  int zb = (Nn + 255) >> 8;
  int b = blockIdx.x;
  int t = threadIdx.x;
  if (b < zb) {
    int i = b * 256 + t;
    if (i < Nn) deg[i] = 0;
  } else if (b < zb + 768) {
    int i = (b - zb) * 256 + t;  // 0..196607
    const float* W;
    unsigned short* WT;
    int K, N, j;
    if (i < 32768) {            // W1a: 128x256
      W = W1a; WT = w1t; K = 128; N = 256; j = i;
    } else if (i < 98304) {     // W2a: 256x256
      W = W2a; WT = w2t; K = 256; N = 256; j = i - 32768;
    } else if (i < 163840) {    // W1b: 256x256
      W = W1b; WT = w3t; K = 256; N = 256; j = i - 98304;
    } else {                    // W2b: 256x128
      W = W2b; WT = w4t; K = 256; N = 128; j = i - 163840;
    }
    int k = j / N, n = j - k * N;
    WT[n * K + k] = f2bf(W[j]);
  } else {
    long long i = (long long)(b - zb - 768) * 256 + t;
    long long stride = (long long)(gridDim.x - zb - 768) * 256;
    for (; i < n4; i += stride) {
      float4 v = ((const float4*)x)[i];
      u16x4 o;
      o.x = f2bf(v.x); o.y = f2bf(v.y); o.z = f2bf(v.z); o.w = f2bf(v.w);
      ((u16x4*)xb)[i] = o;
    }
  }
}

// ------------------------- aggregation -------------------------------------
// D=128: one wave/node; 16 lanes per row (u16x8 = 16B/lane), 4 rows per load
// instruction, unroll 2 -> 8 rows in flight. Self row folded in as virtual
// neighbor j=0; tail mask-predicated via fma sel.
__global__ __launch_bounds__(256) void agg_bf16_128(
    unsigned short* __restrict__ out, const unsigned short* __restrict__ xb,
    const int* __restrict__ offs, const int* __restrict__ esrc, int Nn) {
  int node = blockIdx.x * 4 + (threadIdx.x >> 6);
  if (node >= Nn) return;
  int lane = threadIdx.x & 63;
  int sub = lane >> 4, l16 = lane & 15;
  int beg = offs[node], end = offs[node + 1];
  int total = end - beg + 1;  // incl. self
  const unsigned short* xp = xb + l16 * 8;
  float acc[8] = {};
  for (int j0 = 0; j0 < total; j0 += 8) {
#pragma unroll
    for (int u = 0; u < 2; ++u) {
      int j = j0 + u * 4 + sub;
      int rv = esrc[beg + j - (j > 0)];  // safe: reads at most +8 past end
      long long row = (j > 0 && j < total) ? rv : node;
      float sel = (j < total) ? 1.f : 0.f;
      u16x8 v = *(const u16x8*)(xp + row * 128);
#pragma unroll
      for (int k = 0; k < 8; ++k)
        acc[k] = fmaf(bf2f(v[k]), sel, acc[k]);
    }
  }
#pragma unroll
  for (int k = 0; k < 8; ++k) acc[k] += __shfl_xor(acc[k], 16);
#pragma unroll
  for (int k = 0; k < 8; ++k) acc[k] += __shfl_xor(acc[k], 32);
  if (sub == 0) {
    u16x8 o;
#pragma unroll
    for (int k = 0; k < 8; ++k) o[k] = f2bf(acc[k]);
    *(u16x8*)(out + (long long)node * 128 + l16 * 8) = o;
  }
}

// D=256: one wave/node; 32 lanes per row (u16x8 = 16B/lane), 2 rows per load
// instruction, unroll 4 -> 8 rows (4KB) in flight.
__global__ __launch_bounds__(256) void agg_bf16_256(
    unsigned short* __restrict__ out, const unsigned short* __restrict__ h,
    const int* __restrict__ offs, const int* __restrict__ esrc, int Nn) {
  int node = blockIdx.x * 4 + (threadIdx.x >> 6);
  if (node >= Nn) return;
  int lane = threadIdx.x & 63;
  int sub = lane >> 5, l32 = lane & 31;
  int beg = offs[node], end = offs[node + 1];
  int total = end - beg + 1;  // incl. self
  const unsigned short* hp = h + l32 * 8;
  float acc[8] = {};
  for (int j0 = 0; j0 < total; j0 += 8) {
#pragma unroll
    for (int u = 0; u < 4; ++u) {
      int j = j0 + u * 2 + sub;
      int rv = esrc[beg + j - (j > 0)];
      long long row = (j > 0 && j < total) ? rv : node;
      float sel = (j < total) ? 1.f : 0.f;
      u16x8 v = *(const u16x8*)(hp + row * 256);
#pragma unroll
      for (int k = 0; k < 8; ++k)
        acc[k] = fmaf(bf2f(v[k]), sel, acc[k]);
    }
  }
#pragma unroll
  for (int k = 0; k < 8; ++k) acc[k] += __shfl_xor(acc[k], 32);
  if (sub == 0) {
    u16x8 o;
#pragma unroll
    for (int k = 0; k < 8; ++k) o[k] = f2bf(acc[k]);
    *(u16x8*)(out + (long long)node * 256 + l32 * 8) = o;
  }
}

// ----------------------------- MFMA GEMM ------------------------------------
// C[M,N] = A[M,K]@B[K,N] + bias (opt ReLU). A bf16 [M][K], BT bf16 [N][K].
// BM=BN=128, BK=32. 256 threads = 4 waves in 2x2, each wave 64x64 (4x4 tiles
// of 16x16x32 MFMA). global_load_lds width-16 staging.
template <bool RELU, bool OUT_BF16>
__global__ __launch_bounds__(256) void gemm_mfma(
    const unsigned short* __restrict__ A, const unsigned short* __restrict__ BT,
    const float* __restrict__ bias, void* __restrict__ C, int M, int K, int N) {
  __shared__ unsigned short As[128 * 32];
  __shared__ unsigned short Bs[128 * 32];
  const int tid = threadIdx.x;
  const int wave = tid >> 6, lane = tid & 63;
  const int wm = wave & 1, wn = wave >> 1;
  const int quad = lane >> 4, l16 = lane & 15;
  const int rowBase = blockIdx.y * 128;
  const int colBase = blockIdx.x * 128;

  const int srow = wave * 32 + (lane >> 2);
  const int koff = (lane & 3) * 8;
  long long ra0 = min(rowBase + srow, M - 1);
  long long ra1 = min(rowBase + srow + 16, M - 1);
  const unsigned short* ga0 = A + ra0 * K + koff;
  const unsigned short* ga1 = A + ra1 * K + koff;
  const unsigned short* gb0 = BT + (long long)(colBase + srow) * K + koff;
  const unsigned short* gb1 = BT + (long long)(colBase + srow + 16) * K + koff;
  unsigned short* la0 = As + wave * 1024;
  unsigned short* la1 = As + wave * 1024 + 512;
  unsigned short* lb0 = Bs + wave * 1024;
  unsigned short* lb1 = Bs + wave * 1024 + 512;

  f32x4 acc[4][4] = {};

  for (int k0 = 0; k0 < K; k0 += 32) {
    G2L16(ga0, la0);
    G2L16(ga1, la1);
    G2L16(gb0, lb0);
    G2L16(gb1, lb1);
    ga0 += 32; ga1 += 32; gb0 += 32; gb1 += 32;
    __syncthreads();

    bf16x8 af[4], bfr[4];
    const int arow = wm * 64 + l16;
    const int brow = wn * 64 + l16;
#pragma unroll
    for (int mi = 0; mi < 4; ++mi)
      af[mi] = *(const bf16x8*)(As + (arow + mi * 16) * 32 + quad * 8);
#pragma unroll
    for (int ni = 0; ni < 4; ++ni)
      bfr[ni] = *(const bf16x8*)(Bs + (brow + ni * 16) * 32 + quad * 8);
#pragma unroll
    for (int mi = 0; mi < 4; ++mi)
#pragma unroll
      for (int ni = 0; ni < 4; ++ni)
        acc[mi][ni] = __builtin_amdgcn_mfma_f32_16x16x32_bf16(
            af[mi], bfr[ni], acc[mi][ni], 0, 0, 0);
    __syncthreads();
  }

  float bias_v[4];
#pragma unroll
  for (int ni = 0; ni < 4; ++ni)
    bias_v[ni] = bias[colBase + wn * 64 + ni * 16 + l16];
#pragma unroll
  for (int mi = 0; mi < 4; ++mi) {
#pragma unroll
    for (int r = 0; r < 4; ++r) {
      int row = rowBase + wm * 64 + mi * 16 + quad * 4 + r;
      if (row < M) {
#pragma unroll
        for (int ni = 0; ni < 4; ++ni) {
          float o = acc[mi][ni][r] + bias_v[ni];
          if (RELU) o = fmaxf(o, 0.f);
          int col = colBase + wn * 64 + ni * 16 + l16;
          if (OUT_BF16)
            ((unsigned short*)C)[(long long)row * N + col] = f2bf(o);
          else
            ((float*)C)[(long long)row * N + col] = o;
        }
      }
    }
  }
}

// ---------------------------------------------------------------------------
extern "C" void kernel_launch(void* const* d_in, const int* in_sizes, int n_in,
                              void* d_out, int out_size, void* d_ws, size_t ws_size,
                              hipStream_t stream) {
  const float* x   = (const float*)d_in[0];
  const float* W1a = (const float*)d_in[1];
  const float* b1a = (const float*)d_in[2];
  const float* W2a = (const float*)d_in[3];
  const float* b2a = (const float*)d_in[4];
  const float* W1b = (const float*)d_in[5];
  const float* b1b = (const float*)d_in[6];
  const float* W2b = (const float*)d_in[7];
  const float* b2b = (const float*)d_in[8];
  const int*   ei  = (const int*)d_in[9];  // [2,E]: row0=src, row1=dst

  const int Nn = in_sizes[0] / 128;  // 50000
  const int E  = in_sizes[9] / 2;    // 600000
  float* out = (float*)d_out;

  // workspace
  unsigned short* t   = (unsigned short*)d_ws;     // N*256 bf16
  unsigned short* h   = t  + (size_t)Nn * 256;     // N*256
  unsigned short* g0  = h  + (size_t)Nn * 256;     // N*128
  unsigned short* g1  = g0 + (size_t)Nn * 128;     // N*256
  unsigned short* t2  = g1 + (size_t)Nn * 256;     // N*256
  unsigned short* xb  = t2 + (size_t)Nn * 256;     // N*128
  unsigned short* w1t = xb + (size_t)Nn * 128;     // 256*128
  unsigned short* w2t = w1t + 256 * 128;           // 256*256
  unsigned short* w3t = w2t + 256 * 256;           // 256*256
  unsigned short* w4t = w3t + 256 * 256;           // 128*256
  int* deg  = (int*)(w4t + 128 * 256);
  int* offs = deg + Nn;        // N+1
  int* pos  = offs + Nn + 1;   // N
  int* esrc = pos + Nn;        // E (+8 overshoot pad provided by bsum below)
  int* bsum = esrc + E;        // ~196

  dim3 blk(256);
  int nb = (Nn + 255) / 256;  // 196 scan blocks

  // prep: zero deg + cast x->bf16 + weight transposes (one launch)
  prep<<<nb + 768 + 2048, blk, 0, stream>>>(deg, Nn, x, xb,
                                            (long long)Nn * 128 / 4,
                                            W1a, W2a, W1b, W2b,
                                            w1t, w2t, w3t, w4t);
  // CSR build
  hist<<<(E + 255) / 256, blk, 0, stream>>>(ei, deg, E);
  block_sums<<<nb, blk, 0, stream>>>(deg, bsum, Nn);
  scan_bsums<<<1, blk, 0, stream>>>(bsum, nb);
  block_scan<<<nb, blk, 0, stream>>>(deg, bsum, offs, pos, Nn);
  fill_csr<<<(E + 255) / 256, blk, 0, stream>>>(ei, pos, esrc, E);

  int aggBlocks = (Nn + 3) / 4;
  int gy = (Nn + 127) / 128;

  // layer 0
  agg_bf16_128<<<aggBlocks, blk, 0, stream>>>(g0, xb, offs, esrc, Nn);
  gemm_mfma<true, true><<<dim3(2, gy), blk, 0, stream>>>(g0, w1t, b1a, t, Nn, 128, 256);
  gemm_mfma<true, true><<<dim3(2, gy), blk, 0, stream>>>(t, w2t, b2a, h, Nn, 256, 256);

  // layer 1
  agg_bf16_256<<<aggBlocks, blk, 0, stream>>>(g1, h, offs, esrc, Nn);
  gemm_mfma<true, true><<<dim3(2, gy), blk, 0, stream>>>(g1, w3t, b1b, t2, Nn, 256, 256);
  gemm_mfma<false, false><<<dim3(1, gy), blk, 0, stream>>>(t2, w4t, b2b, out, Nn, 256, 128);
}

// Round 8
// 294.039 us; speedup vs baseline: 1.1412x; 1.0616x over previous
//
#include <hip/hip_runtime.h>

// ---------------------------------------------------------------------------
// GIN 2-layer forward. R8: fused MLP kernels (GEMM->ReLU->GEMM in one block,
// T tile in LDS, eliminates t/t2 round-trips and A re-reads), 16-deep agg.
// bf16 MFMA (16x16x32), CSR-gather aggregation, hierarchical scan.
// N=50000, E=600000, dims 128->256->256->256->128.
// ---------------------------------------------------------------------------

typedef __bf16 bf16x8 __attribute__((ext_vector_type(8)));
typedef float f32x4 __attribute__((ext_vector_type(4)));
typedef unsigned short u16x8 __attribute__((ext_vector_type(8)));
typedef unsigned short u16x4 __attribute__((ext_vector_type(4)));
typedef unsigned int uint32;

__device__ __forceinline__ unsigned short f2bf(float f) {
  uint32 u = __builtin_bit_cast(uint32, f);
  u += 0x7FFFu + ((u >> 16) & 1u);  // RNE
  return (unsigned short)(u >> 16);
}
__device__ __forceinline__ float bf2f(unsigned short h) {
  return __builtin_bit_cast(float, (uint32)h << 16);
}

#define G2L16(gp, lp)                                                        \
  __builtin_amdgcn_global_load_lds(                                          \
      (const __attribute__((address_space(1))) void*)(gp),                   \
      (__attribute__((address_space(3))) void*)(lp), 16, 0, 0)

// ---------------------------- CSR build ------------------------------------
__global__ void hist(const int* __restrict__ eidx, int* __restrict__ deg, int E) {
  int e = blockIdx.x * blockDim.x + threadIdx.x;
  if (e < E) atomicAdd(&deg[eidx[e + E]], 1);
}

__global__ __launch_bounds__(256) void block_sums(const int* __restrict__ deg,
                                                  int* __restrict__ bsum, int Nn) {
  __shared__ int sm[256];
  int t = threadIdx.x;
  int i = blockIdx.x * 256 + t;
  sm[t] = (i < Nn) ? deg[i] : 0;
  __syncthreads();
#pragma unroll
  for (int off = 128; off > 0; off >>= 1) {
    if (t < off) sm[t] += sm[t + off];
    __syncthreads();
  }
  if (t == 0) bsum[blockIdx.x] = sm[0];
}

__global__ __launch_bounds__(256) void scan_bsums(int* __restrict__ bsum, int nb) {
  __shared__ int sm[256];
  int t = threadIdx.x;
  int v = (t < nb) ? bsum[t] : 0;
  sm[t] = v;
  __syncthreads();
#pragma unroll
  for (int off = 1; off < 256; off <<= 1) {
    int add = (t >= off) ? sm[t - off] : 0;
    __syncthreads();
    sm[t] += add;
    __syncthreads();
  }
  if (t < nb) bsum[t] = sm[t] - v;  // exclusive
}

__global__ __launch_bounds__(256) void block_scan(const int* __restrict__ deg,
                                                  const int* __restrict__ bsum,
                                                  int* __restrict__ offs,
                                                  int* __restrict__ pos, int Nn) {
  __shared__ int sm[256];
  int t = threadIdx.x;
  int i = blockIdx.x * 256 + t;
  int v = (i < Nn) ? deg[i] : 0;
  sm[t] = v;
  __syncthreads();
#pragma unroll
  for (int off = 1; off < 256; off <<= 1) {
    int add = (t >= off) ? sm[t - off] : 0;
    __syncthreads();
    sm[t] += add;
    __syncthreads();
  }
  int ex = bsum[blockIdx.x] + sm[t] - v;
  if (i < Nn) {
    offs[i] = ex;
    pos[i] = ex;
    if (i == Nn - 1) offs[Nn] = ex + v;
  }
}

__global__ void fill_csr(const int* __restrict__ eidx, int* __restrict__ pos,
                         int* __restrict__ esrc, int E) {
  int e = blockIdx.x * blockDim.x + threadIdx.x;
  if (e < E) {
    int s = eidx[e];
    int d = eidx[e + E];
    int p = atomicAdd(&pos[d], 1);
    esrc[p] = s;
  }
}

// --------------- fused prep: zero deg + cast x->bf16 + transposes -----------
__global__ __launch_bounds__(256) void prep(
    int* __restrict__ deg, int Nn,
    const float* __restrict__ x, unsigned short* __restrict__ xb, long long n4,
    const float* __restrict__ W1a, const float* __restrict__ W2a,
    const float* __restrict__ W1b, const float* __restrict__ W2b,
    unsigned short* __restrict__ w1t, unsigned short* __restrict__ w2t,
    unsigned short* __restrict__ w3t, unsigned short* __restrict__ w4t) {
  int zb = (Nn + 255) >> 8;
  int b = blockIdx.x;
  int t = threadIdx.x;
  if (b < zb) {
    int i = b * 256 + t;
    if (i < Nn) deg[i] = 0;
  } else if (b < zb + 768) {
    int i = (b - zb) * 256 + t;  // 0..196607
    const float* W;
    unsigned short* WT;
    int K, N, j;
    if (i < 32768) {            // W1a: 128x256
      W = W1a; WT = w1t; K = 128; N = 256; j = i;
    } else if (i < 98304) {     // W2a: 256x256
      W = W2a; WT = w2t; K = 256; N = 256; j = i - 32768;
    } else if (i < 163840) {    // W1b: 256x256
      W = W1b; WT = w3t; K = 256; N = 256; j = i - 98304;
    } else {                    // W2b: 256x128
      W = W2b; WT = w4t; K = 256; N = 128; j = i - 163840;
    }
    int k = j / N, n = j - k * N;
    WT[n * K + k] = f2bf(W[j]);
  } else {
    long long i = (long long)(b - zb - 768) * 256 + t;
    long long stride = (long long)(gridDim.x - zb - 768) * 256;
    for (; i < n4; i += stride) {
      float4 v = ((const float4*)x)[i];
      u16x4 o;
      o.x = f2bf(v.x); o.y = f2bf(v.y); o.z = f2bf(v.z); o.w = f2bf(v.w);
      ((u16x4*)xb)[i] = o;
    }
  }
}

// ------------------------- aggregation -------------------------------------
// D=128: one wave/node; 16 lanes/row (u16x8), 4 rows/load-instr, 16 in flight.
__global__ __launch_bounds__(256) void agg_bf16_128(
    unsigned short* __restrict__ out, const unsigned short* __restrict__ xb,
    const int* __restrict__ offs, const int* __restrict__ esrc, int Nn) {
  int node = blockIdx.x * 4 + (threadIdx.x >> 6);
  if (node >= Nn) return;
  int lane = threadIdx.x & 63;
  int sub = lane >> 4, l16 = lane & 15;
  int beg = offs[node], end = offs[node + 1];
  int total = end - beg + 1;  // incl. self
  const unsigned short* xp = xb + l16 * 8;
  float acc[8] = {};
  for (int j0 = 0; j0 < total; j0 += 16) {
#pragma unroll
    for (int u = 0; u < 4; ++u) {
      int j = j0 + u * 4 + sub;
      int rv = esrc[beg + j - (j > 0)];  // reads at most +16 past end (safe)
      long long row = (j > 0 && j < total) ? rv : node;
      float sel = (j < total) ? 1.f : 0.f;
      u16x8 v = *(const u16x8*)(xp + row * 128);
#pragma unroll
      for (int k = 0; k < 8; ++k)
        acc[k] = fmaf(bf2f(v[k]), sel, acc[k]);
    }
  }
#pragma unroll
  for (int k = 0; k < 8; ++k) acc[k] += __shfl_xor(acc[k], 16);
#pragma unroll
  for (int k = 0; k < 8; ++k) acc[k] += __shfl_xor(acc[k], 32);
  if (sub == 0) {
    u16x8 o;
#pragma unroll
    for (int k = 0; k < 8; ++k) o[k] = f2bf(acc[k]);
    *(u16x8*)(out + (long long)node * 128 + l16 * 8) = o;
  }
}

// D=256: one wave/node; 32 lanes/row (u16x8), 2 rows/load-instr, 16 in flight.
__global__ __launch_bounds__(256) void agg_bf16_256(
    unsigned short* __restrict__ out, const unsigned short* __restrict__ h,
    const int* __restrict__ offs, const int* __restrict__ esrc, int Nn) {
  int node = blockIdx.x * 4 + (threadIdx.x >> 6);
  if (node >= Nn) return;
  int lane = threadIdx.x & 63;
  int sub = lane >> 5, l32 = lane & 31;
  int beg = offs[node], end = offs[node + 1];
  int total = end - beg + 1;  // incl. self
  const unsigned short* hp = h + l32 * 8;
  float acc[8] = {};
  for (int j0 = 0; j0 < total; j0 += 16) {
#pragma unroll
    for (int u = 0; u < 8; ++u) {
      int j = j0 + u * 2 + sub;
      int rv = esrc[beg + j - (j > 0)];
      long long row = (j > 0 && j < total) ? rv : node;
      float sel = (j < total) ? 1.f : 0.f;
      u16x8 v = *(const u16x8*)(hp + row * 256);
#pragma unroll
      for (int k = 0; k < 8; ++k)
        acc[k] = fmaf(bf2f(v[k]), sel, acc[k]);
    }
  }
#pragma unroll
  for (int k = 0; k < 8; ++k) acc[k] += __shfl_xor(acc[k], 32);
  if (sub == 0) {
    u16x8 o;
#pragma unroll
    for (int k = 0; k < 8; ++k) o[k] = f2bf(acc[k]);
    *(u16x8*)(out + (long long)node * 256 + l32 * 8) = o;
  }
}

// --------------------------- fused MLP -------------------------------------
// C = relu?(relu(A@W1+b1)@W2+b2). A bf16 [M][K1], W1^T bf16 [256][K1],
// W2^T bf16 [N2][256]. Block = 64 rows x full width. 4 waves, 1x4 col split.
// T (64x256 bf16, ld 264) lives in LDS between stages.
template <int K1, int N2, bool OUT_BF16>
__global__ __launch_bounds__(256) void fused_mlp(
    const unsigned short* __restrict__ A,
    const unsigned short* __restrict__ BT1, const float* __restrict__ b1,
    const unsigned short* __restrict__ BT2, const float* __restrict__ b2,
    void* __restrict__ Cout, int M) {
  __shared__ unsigned short As[64 * 32];    // 4 KB
  __shared__ unsigned short Bs[256 * 32];   // 16 KB
  __shared__ unsigned short Ts[64 * 264];   // 33.8 KB (ld 264 breaks banks)
  const int tid = threadIdx.x;
  const int wave = tid >> 6, lane = tid & 63;
  const int quad = lane >> 4, l16 = lane & 15;
  const int rowBase = blockIdx.x * 64;
  const int r16 = lane >> 2;  // staging row within 16-chunk
  const int kq = lane & 3;    // staging 8-elem k chunk

  // ---- stage 1: T = relu(A @ W1 + b1) ----
  long long arow = min(rowBase + wave * 16 + r16, M - 1);
  const unsigned short* ga = A + arow * K1 + kq * 8;
  const unsigned short* gb = BT1 + (long long)(wave * 64 + r16) * K1 + kq * 8;
  unsigned short* la = As + wave * 16 * 32;
  f32x4 acc[4][4] = {};
  for (int k0 = 0; k0 < K1; k0 += 32) {
    G2L16(ga, la);
    ga += 32;
#pragma unroll
    for (int c = 0; c < 4; ++c)
      G2L16(gb + (long long)(16 * c) * K1, Bs + (wave * 64 + 16 * c) * 32);
    gb += 32;
    __syncthreads();
    bf16x8 af[4], bfr[4];
#pragma unroll
    for (int mi = 0; mi < 4; ++mi)
      af[mi] = *(const bf16x8*)(As + (mi * 16 + l16) * 32 + quad * 8);
#pragma unroll
    for (int ni = 0; ni < 4; ++ni)
      bfr[ni] = *(const bf16x8*)(Bs + (wave * 64 + ni * 16 + l16) * 32 + quad * 8);
#pragma unroll
    for (int mi = 0; mi < 4; ++mi)
#pragma unroll
      for (int ni = 0; ni < 4; ++ni)
        acc[mi][ni] = __builtin_amdgcn_mfma_f32_16x16x32_bf16(
            af[mi], bfr[ni], acc[mi][ni], 0, 0, 0);
    __syncthreads();
  }
  // epilogue 1 -> Ts (C-layout: col=l16, row=quad*4+r within 16x16 tile)
#pragma unroll
  for (int ni = 0; ni < 4; ++ni) {
    int col = wave * 64 + ni * 16 + l16;
    float bv = b1[col];
#pragma unroll
    for (int mi = 0; mi < 4; ++mi)
#pragma unroll
      for (int r = 0; r < 4; ++r) {
        int row = mi * 16 + quad * 4 + r;
        Ts[row * 264 + col] = f2bf(fmaxf(acc[mi][ni][r] + bv, 0.f));
      }
  }
  __syncthreads();

  // ---- stage 2: C = T @ W2 + b2 ----
  constexpr int NI2 = N2 / 64;       // 16-col tiles per wave
  const int wcol = wave * (N2 / 4);  // this wave's column base
  const unsigned short* gb2 = BT2 + (long long)(wcol + r16) * 256 + kq * 8;
  f32x4 acc2[4][NI2] = {};
  for (int k2 = 0; k2 < 256; k2 += 32) {
#pragma unroll
    for (int c = 0; c < NI2; ++c)
      G2L16(gb2 + (long long)(16 * c) * 256, Bs + (wcol + 16 * c) * 32);
    gb2 += 32;
    __syncthreads();
    bf16x8 af[4], bfr[NI2];
#pragma unroll
    for (int mi = 0; mi < 4; ++mi)
      af[mi] = *(const bf16x8*)(Ts + (mi * 16 + l16) * 264 + k2 + quad * 8);
#pragma unroll
    for (int ni = 0; ni < NI2; ++ni)
      bfr[ni] = *(const bf16x8*)(Bs + (wcol + ni * 16 + l16) * 32 + quad * 8);
#pragma unroll
    for (int mi = 0; mi < 4; ++mi)
#pragma unroll
      for (int ni = 0; ni < NI2; ++ni)
        acc2[mi][ni] = __builtin_amdgcn_mfma_f32_16x16x32_bf16(
            af[mi], bfr[ni], acc2[mi][ni], 0, 0, 0);
    __syncthreads();
  }
  // epilogue 2
#pragma unroll
  for (int ni = 0; ni < NI2; ++ni) {
    int col = wcol + ni * 16 + l16;
    float bv = b2[col];
#pragma unroll
    for (int mi = 0; mi < 4; ++mi)
#pragma unroll
      for (int r = 0; r < 4; ++r) {
        int row = rowBase + mi * 16 + quad * 4 + r;
        if (row < M) {
          float o = acc2[mi][ni][r] + bv;
          if (OUT_BF16)
            ((unsigned short*)Cout)[(long long)row * N2 + col] = f2bf(fmaxf(o, 0.f));
          else
            ((float*)Cout)[(long long)row * N2 + col] = o;
        }
      }
  }
}

// ---------------------------------------------------------------------------
extern "C" void kernel_launch(void* const* d_in, const int* in_sizes, int n_in,
                              void* d_out, int out_size, void* d_ws, size_t ws_size,
                              hipStream_t stream) {
  const float* x   = (const float*)d_in[0];
  const float* W1a = (const float*)d_in[1];
  const float* b1a = (const float*)d_in[2];
  const float* W2a = (const float*)d_in[3];
  const float* b2a = (const float*)d_in[4];
  const float* W1b = (const float*)d_in[5];
  const float* b1b = (const float*)d_in[6];
  const float* W2b = (const float*)d_in[7];
  const float* b2b = (const float*)d_in[8];
  const int*   ei  = (const int*)d_in[9];  // [2,E]: row0=src, row1=dst

  const int Nn = in_sizes[0] / 128;  // 50000
  const int E  = in_sizes[9] / 2;    // 600000
  float* out = (float*)d_out;

  // workspace
  unsigned short* h   = (unsigned short*)d_ws;     // N*256 bf16
  unsigned short* g0  = h  + (size_t)Nn * 256;     // N*128
  unsigned short* g1  = g0 + (size_t)Nn * 128;     // N*256
  unsigned short* xb  = g1 + (size_t)Nn * 256;     // N*128
  unsigned short* w1t = xb + (size_t)Nn * 128;     // 256*128
  unsigned short* w2t = w1t + 256 * 128;           // 256*256
  unsigned short* w3t = w2t + 256 * 256;           // 256*256
  unsigned short* w4t = w3t + 256 * 256;           // 128*256
  int* deg  = (int*)(w4t + 128 * 256);
  int* offs = deg + Nn;        // N+1
  int* pos  = offs + Nn + 1;   // N
  int* esrc = pos + Nn;        // E
  int* bsum = esrc + E;        // ~196 (also absorbs agg index overshoot)

  dim3 blk(256);
  int nb = (Nn + 255) / 256;  // 196 scan blocks

  // prep: zero deg + cast x->bf16 + weight transposes (one launch)
  prep<<<nb + 768 + 2048, blk, 0, stream>>>(deg, Nn, x, xb,
                                            (long long)Nn * 128 / 4,
                                            W1a, W2a, W1b, W2b,
                                            w1t, w2t, w3t, w4t);
  // CSR build
  hist<<<(E + 255) / 256, blk, 0, stream>>>(ei, deg, E);
  block_sums<<<nb, blk, 0, stream>>>(deg, bsum, Nn);
  scan_bsums<<<1, blk, 0, stream>>>(bsum, nb);
  block_scan<<<nb, blk, 0, stream>>>(deg, bsum, offs, pos, Nn);
  fill_csr<<<(E + 255) / 256, blk, 0, stream>>>(ei, pos, esrc, E);

  int aggBlocks = (Nn + 3) / 4;
  int mlpBlocks = (Nn + 63) / 64;  // 782

  // layer 0: g0 = agg(x); h = relu(mlp(g0))
  agg_bf16_128<<<aggBlocks, blk, 0, stream>>>(g0, xb, offs, esrc, Nn);
  fused_mlp<128, 256, true><<<mlpBlocks, blk, 0, stream>>>(
      g0, w1t, b1a, w2t, b2a, h, Nn);

  // layer 1: g1 = agg(h); out = mlp(g1)
  agg_bf16_256<<<aggBlocks, blk, 0, stream>>>(g1, h, offs, esrc, Nn);
  fused_mlp<256, 128, false><<<mlpBlocks, blk, 0, stream>>>(
      g1, w3t, b1b, w4t, b2b, out, Nn);
}